// Round 1
// baseline (206.170 us; speedup 1.0000x reference)
//
#include <hip/hip_runtime.h>

#define B_ 2048
#define T_ 500
#define N_ 64
#define BT (B_ * T_)

// ---------------------------------------------------------------------------
// Kernel 1: row sums.  S[r] = sum_n input[r*64 + n],  r = b*T + t.
// One thread per float4 chunk (16 chunks per row -> 16 lanes cooperate per
// row), fully coalesced: each wave reads 1 KB contiguous per instruction.
// ---------------------------------------------------------------------------
__global__ __launch_bounds__(256) void rowsum_kernel(const float* __restrict__ in,
                                                     float* __restrict__ S) {
    long long gid = (long long)blockIdx.x * 256 + threadIdx.x;  // chunk index
    const float4* p = (const float4*)in;
    float4 v = p[gid];
    float s = (v.x + v.y) + (v.z + v.w);
    // reduce over the 16 lanes that share one row
    s += __shfl_xor(s, 1);
    s += __shfl_xor(s, 2);
    s += __shfl_xor(s, 4);
    s += __shfl_xor(s, 8);
    if ((threadIdx.x & 15) == 0) S[gid >> 4] = s;
}

// ---------------------------------------------------------------------------
// Izhikevich Euler step, matching the reference's association order exactly.
// DT = 0.25; all neuron types have a = 0.02 -> DT*a = 0.005f.
// Returns spike z; updates v,u in place.
// ---------------------------------------------------------------------------
__device__ __forceinline__ float izh(float& v, float& u, float I,
                                     float b, float c, float d) {
    float t  = 0.04f * v * v + 5.0f * v + 140.0f - u + I;
    float v_ = v + 0.25f * t;
    float u_ = u + 0.005f * (b * v - u);
    float z  = (v_ >= 30.0f) ? 1.0f : 0.0f;
    v = (v_ >= 30.0f) ? c : v_;
    u = u_ + z * d;
    return z;
}

// ---------------------------------------------------------------------------
// Kernel 2: the sequential scan. One thread per batch element, both channels
// (two independent dependency chains -> ILP). 2048 threads total; block=64 so
// the 32 waves spread over 32 CUs. Latency-bound by design.
// NOTE: S may alias out[0..BT) (o_spikes region). Per-thread, the prefetch of
// S[t+4..t+7] is issued before the stores to [t..t+3]; no __restrict__ on
// S/out so the compiler preserves that order.
// ---------------------------------------------------------------------------
__global__ __launch_bounds__(64) void scan_kernel(const float* S,
                                                  const float* __restrict__ w24,
                                                  float* out) {
    int b = blockIdx.x * 64 + threadIdx.x;
    if (b >= B_) return;

    const float w0 = w24[0],  w1 = w24[1],  w2 = w24[2],  w3 = w24[3];
    const float w4 = w24[4],  w5 = w24[5],  w6 = w24[6];
    const float w8 = w24[8],  w9 = w24[9],  w10 = w24[10], w11 = w24[11];
    const float w12 = w24[12], w13 = w24[13], w16 = w24[16], w17 = w24[17];
    const float w18 = w24[18], w20 = w24[20], w23 = w24[23];

    // channel 1 state
    float vL = -70.f, uL = -14.f, zL = 0.f;
    float vE = -64.f, uE = -16.f;
    float vI = -64.f, uI = -16.f;
    float vT = -70.f, uT = -14.f, zT = 0.f;
    float vM = -64.f, uM = -16.f;
    // channel 2 state
    float vL2 = -70.f, uL2 = -14.f, zL2 = 0.f;
    float vE2 = -64.f, uE2 = -16.f;
    float vI2 = -64.f, uI2 = -16.f;
    float vT2 = -70.f, uT2 = -14.f, zT2 = 0.f;
    float vM2 = -64.f, uM2 = -16.f;

    const float4* Srow = (const float4*)(S + (size_t)b * T_);
    float* p0 = out + (size_t)b * T_;            // o_spikes  [B,T]
    float* p1 = p0 + (size_t)BT;                 // v         [B,T]
    float* p2 = p0 + (size_t)2 * BT;             // o_spikes2 [B,T]
    float* p3 = p0 + (size_t)3 * BT;             // v2        [B,T]
    float4* p4 = (float4*)out + (size_t)BT + (size_t)b * T_;      // o_spikes_o [B,T,4]
    float4* p5 = (float4*)out + (size_t)2 * BT + (size_t)b * T_;  // v_o        [B,T,4]

    float4 sc = Srow[0];
    for (int i = 0; i < T_ / 4; ++i) {
        float4 sn = sc;
        if (i + 1 < T_ / 4) sn = Srow[i + 1];  // prefetch next 4 steps
        float sv[4] = {sc.x, sc.y, sc.z, sc.w};
#pragma unroll
        for (int k = 0; k < 4; ++k) {
            int t = 4 * i + k;
            float Ssum = sv[k];
            float zp  = Ssum * w0;
            float zp2 = Ssum * w12;
            // --- channel 1 ---
            float z2 = izh(vL, uL, w2 * (zp * w1) + w3 * zL, 0.20f, -65.f, 6.f);
            float z3 = izh(vE, uE, zp * w4 + z2 * w5,        0.25f, -55.f, 0.05f);
            float z4 = izh(vI, uI, z3 * w6,                  0.25f, -65.f, 6.f);
            float z5 = izh(vT, uT, w9 * (z3 * w8) + w10 * zT,0.20f, -50.f, 2.f);
            float z6 = izh(vM, uM, z5 * w11,                 0.25f, -65.f, 6.f);
            zL = z2; zT = z5;
            // --- channel 2 ---
            float z22 = izh(vL2, uL2, w2 * (zp2 * w13) + w3 * zL2, 0.20f, -65.f, 6.f);
            float z32 = izh(vE2, uE2, zp2 * w16 + z22 * w17,       0.25f, -55.f, 0.05f);
            float z42 = izh(vI2, uI2, z32 * w18,                   0.25f, -65.f, 6.f);
            float z52 = izh(vT2, uT2, w9 * (z32 * w20) + w10 * zT2,0.20f, -50.f, 2.f);
            float z62 = izh(vM2, uM2, z52 * w23,                   0.25f, -65.f, 6.f);
            zL2 = z22; zT2 = z52;
            (void)z42;

            p0[t] = z6;
            p1[t] = vM;
            p2[t] = z62;
            p3[t] = vM2;
            p4[t] = make_float4(z2, z3, z4, z5);
            p5[t] = make_float4(vL, vE, vI, vT);
        }
        sc = sn;
    }
}

extern "C" void kernel_launch(void* const* d_in, const int* in_sizes, int n_in,
                              void* d_out, int out_size, void* d_ws, size_t ws_size,
                              hipStream_t stream) {
    const float* in = (const float*)d_in[0];
    const float* w  = (const float*)d_in[1];
    float* out = (float*)d_out;

    // S buffer: prefer workspace; fall back to aliasing the o_spikes region
    // of d_out (safe: per-thread reads strictly lead writes in that region,
    // and scan_kernel rewrites every element afterwards).
    float* S = (ws_size >= (size_t)BT * sizeof(float)) ? (float*)d_ws : out;

    // Kernel 1: BT*16 chunk-threads, 256/block -> 64000 blocks (exact).
    rowsum_kernel<<<(BT * 16) / 256, 256, 0, stream>>>(in, S);

    // Kernel 2: one thread per batch element; 64/block over 32 blocks so the
    // 32 waves land on 32 distinct CUs.
    scan_kernel<<<(B_ + 63) / 64, 64, 0, stream>>>(S, w, out);
}